// Round 6
// baseline (333.418 us; speedup 1.0000x reference)
//
#include <hip/hip_runtime.h>
#include <stdint.h>

typedef __attribute__((ext_vector_type(8))) short bf16x8;
typedef __attribute__((ext_vector_type(4))) float f32x4;

__device__ __forceinline__ uint32_t f2bf(float f) {
    uint32_t u = __builtin_bit_cast(uint32_t, f);
    u += 0x7fffu + ((u >> 16) & 1u);   // RNE round to bf16
    return u >> 16;
}
__device__ __forceinline__ uint32_t pack2(float a, float b) {
    return f2bf(a) | (f2bf(b) << 16);
}

// Prep 1: reciprocal norms 1/max(||row||, eps).
__global__ __launch_bounds__(256) void prep_norms(const float* __restrict__ qe,
                                                  const float* __restrict__ pe,
                                                  float* __restrict__ rq,
                                                  float* __restrict__ rp,
                                                  int Q, int Pn) {
    int gw = (blockIdx.x * 256 + threadIdx.x) >> 6;  // one wave per row
    int lane = threadIdx.x & 63;
    if (gw >= Q + Pn) return;
    const float* src = (gw < Q) ? (qe + (size_t)gw * 128) : (pe + (size_t)(gw - Q) * 128);
    float2 v = *(const float2*)(src + lane * 2);
    float s = v.x * v.x + v.y * v.y;
#pragma unroll
    for (int off = 32; off > 0; off >>= 1) s += __shfl_down(s, off, 64);
    if (lane == 0) {
        float r = 1.0f / fmaxf(sqrtf(s), 1e-8f);
        if (gw < Q) rq[gw] = r; else rp[gw - Q] = r;
    }
}

// Prep 2: fp32 [rows][128] -> bf16 in MFMA-fragment order.
// Fragment (g = 16-row group, c = 32-wide k chunk): lane holds row g*16+(lane&15),
// k = c*32+(lane>>4)*8 .. +7. Flat halfword offset = ((g*4+c)*64 + lane)*8.
// A wave's fragment load in the GEMM = 64 contiguous 16B chunks = 1KB coalesced.
__global__ __launch_bounds__(256) void conv_frag(const float* __restrict__ src,
                                                 unsigned short* __restrict__ dst,
                                                 int ngroups) {
    int t = blockIdx.x * 256 + threadIdx.x;   // one thread per 8 outputs
    if (t >= ngroups * 256) return;
    int g = t >> 8, rem = t & 255;
    int c = rem >> 6, lane = rem & 63;
    int row = g * 16 + (lane & 15);
    int col = c * 32 + ((lane >> 4) << 3);
    const float* s = src + (size_t)row * 128 + col;
    float4 a0 = *(const float4*)s;
    float4 a1 = *(const float4*)(s + 4);
    uint4 pk = { pack2(a0.x, a0.y), pack2(a0.z, a0.w),
                 pack2(a1.x, a1.y), pack2(a1.z, a1.w) };
    *(uint4*)(dst + (size_t)t * 8) = pk;
}

// Main v6: block = 16 q-rows x halfP. 4 waves, each streaming a private 16p strip
// per 64p chunk. B fragments are wave-uniform coalesced 1KB register loads (no LDS,
// no barriers on the B path). Scaled results go to an LDS row-staging buffer;
// every 512p each wave flushes 4 COMPLETE rows as 1KB-contiguous bursts that walk
// p sequentially across flushes -> 16 long sequential write streams per block.
__global__ __launch_bounds__(256) void fused_gemm(
        const unsigned short* __restrict__ Qf, const unsigned short* __restrict__ Pf,
        const int* __restrict__ qid, const int* __restrict__ pid,
        const float* __restrict__ rq, const float* __restrict__ rp,
        float* __restrict__ oxor, float* __restrict__ ocos, int Pn, int halfP) {
    __shared__ __align__(16) float scos[16 * 516];   // padded stride 516: bank-spread
    __shared__ __align__(16) float sxor[16 * 516];   // total 64.5 KB -> 2 blocks/CU

    const int bid = blockIdx.x;
    const int qg = bid >> 1;            // 16-row q group
    const int ph = bid & 1;             // which half of P
    const int pbase0 = ph * halfP;

    const int t = threadIdx.x;
    const int lane = t & 63;
    const int w = t >> 6;
    const int lq = lane & 15;
    const int g4 = (lane >> 4) << 2;    // 0,4,8,12

    // A fragments (same 16 rows for all waves), coalesced 1KB loads
    bf16x8 af[4];
    const unsigned short* abase = Qf + ((size_t)(qg * 4) * 64 + lane) * 8;
#pragma unroll
    for (int kk = 0; kk < 4; ++kk)
        af[kk] = *(const bf16x8*)(abase + kk * 512);

    const float rqv = rq[qg * 16 + lq];
    const int   qv  = qid[qg * 16 + lq];
    const int qrow_base = qg * 16;

    const int nflush = halfP / 512;
    for (int fl = 0; fl < nflush; ++fl) {
        const int fbase = pbase0 + fl * 512;
        // 8 chunks of 64p; wave w owns p-group w within each chunk
#pragma unroll
        for (int c8 = 0; c8 < 8; ++c8) {
            const int p0 = fbase + c8 * 64 + w * 16;   // global p of this fragment
            const int pg = p0 >> 4;
            const unsigned short* bbase = Pf + ((size_t)(pg * 4) * 64 + lane) * 8;
            f32x4 acc = {0.f, 0.f, 0.f, 0.f};
#pragma unroll
            for (int kk = 0; kk < 4; ++kk) {
                bf16x8 bfr = *(const bf16x8*)(bbase + kk * 512);
                // D = Bfrag(16p x 32k) . Afrag(32k x 16q): lane holds q = lane&15,
                // p = pg*16 + (lane>>4)*4 + reg
                acc = __builtin_amdgcn_mfma_f32_16x16x32_bf16(bfr, af[kk], acc, 0, 0, 0);
            }
            const float4 rpv = *(const float4*)(rp + p0 + g4);
            const int4  pv  = *(const int4*)(pid + p0 + g4);
            const int pl = c8 * 64 + w * 16 + g4;      // p_local in [0,512)
            f32x4 c4 = { acc[0]*rqv*rpv.x, acc[1]*rqv*rpv.y,
                         acc[2]*rqv*rpv.z, acc[3]*rqv*rpv.w };
            f32x4 x4 = { qv==pv.x?1.f:0.f, qv==pv.y?1.f:0.f,
                         qv==pv.z?1.f:0.f, qv==pv.w?1.f:0.f };
            *(f32x4*)&scos[lq * 516 + pl] = c4;
            *(f32x4*)&sxor[lq * 516 + pl] = x4;
        }
        __syncthreads();
        // flush: wave w stores rows 4w..4w+3; each row 512 floats = 2x 1KB bursts
#pragma unroll
        for (int r = 0; r < 4; ++r) {
            const int row = w * 4 + r;
            const size_t obase = (size_t)(qrow_base + row) * Pn + fbase;
#pragma unroll
            for (int h = 0; h < 2; ++h) {
                f32x4 vc = *(const f32x4*)&scos[row * 516 + h * 256 + lane * 4];
                f32x4 vx = *(const f32x4*)&sxor[row * 516 + h * 256 + lane * 4];
                *(f32x4*)(ocos + obase + h * 256 + lane * 4) = vc;
                *(f32x4*)(oxor + obase + h * 256 + lane * 4) = vx;
            }
        }
        __syncthreads();
    }
}

extern "C" void kernel_launch(void* const* d_in, const int* in_sizes, int n_in,
                              void* d_out, int out_size, void* d_ws, size_t ws_size,
                              hipStream_t stream) {
    const int*   qid = (const int*)d_in[0];
    const int*   pid = (const int*)d_in[1];
    const float* qe  = (const float*)d_in[2];
    const float* pe  = (const float*)d_in[3];
    const int Q  = in_sizes[0];   // 4096
    const int Pn = in_sizes[1];   // 16384

    // ws layout: Qf bf16 (Q*128), Pf bf16 (P*128), rq (Q), rp (P)  ~= 5.3 MB
    unsigned short* Qf = (unsigned short*)d_ws;
    unsigned short* Pf = Qf + (size_t)Q * 128;
    float* rq = (float*)(Pf + (size_t)Pn * 128);
    float* rp = rq + Q;

    float* oxor = (float*)d_out;
    float* ocos = oxor + (size_t)Q * (size_t)Pn;

    const int qgroups = Q / 16, pgroups = Pn / 16;
    conv_frag<<<qgroups, 256, 0, stream>>>(qe, Qf, qgroups);
    conv_frag<<<pgroups, 256, 0, stream>>>(pe, Pf, pgroups);
    prep_norms<<<(Q + Pn + 3) / 4, 256, 0, stream>>>(qe, pe, rq, rp, Q, Pn);

    const int halfP = Pn / 2;
    const int nblocks = (Q / 16) * 2;   // 512 = 2 blocks/CU, all resident
    fused_gemm<<<nblocks, 256, 0, stream>>>(Qf, Pf, qid, pid, rq, rp, oxor, ocos, Pn, halfP);
}

// Round 7
// 138.776 us; speedup vs baseline: 2.4026x; 2.4026x over previous
//
#include <hip/hip_runtime.h>
#include <stdint.h>

typedef __attribute__((ext_vector_type(8))) short bf16x8;
typedef __attribute__((ext_vector_type(4))) float f32x4;

__device__ __forceinline__ uint32_t f2bf(float f) {
    uint32_t u = __builtin_bit_cast(uint32_t, f);
    u += 0x7fffu + ((u >> 16) & 1u);   // RNE round to bf16
    return u >> 16;
}
__device__ __forceinline__ uint32_t pack2(float a, float b) {
    return f2bf(a) | (f2bf(b) << 16);
}

// Prep 1: reciprocal norms 1/max(||row||, eps).
__global__ __launch_bounds__(256) void prep_norms(const float* __restrict__ qe,
                                                  const float* __restrict__ pe,
                                                  float* __restrict__ rq,
                                                  float* __restrict__ rp,
                                                  int Q, int Pn) {
    int gw = (blockIdx.x * 256 + threadIdx.x) >> 6;  // one wave per row
    int lane = threadIdx.x & 63;
    if (gw >= Q + Pn) return;
    const float* src = (gw < Q) ? (qe + (size_t)gw * 128) : (pe + (size_t)(gw - Q) * 128);
    float2 v = *(const float2*)(src + lane * 2);
    float s = v.x * v.x + v.y * v.y;
#pragma unroll
    for (int off = 32; off > 0; off >>= 1) s += __shfl_down(s, off, 64);
    if (lane == 0) {
        float r = 1.0f / fmaxf(sqrtf(s), 1e-8f);
        if (gw < Q) rq[gw] = r; else rp[gw - Q] = r;
    }
}

// Prep 2: fp32 [rows][128] -> bf16 in MFMA-fragment order.
// Fragment (g = 16-row group, c = 32-wide k chunk): lane holds row g*16+(lane&15),
// k = c*32+(lane>>4)*8 .. +7. Flat halfword offset = ((g*4+c)*64 + lane)*8.
// A wave's fragment load in the GEMM = 64 contiguous 16B chunks = 1KB coalesced.
__global__ __launch_bounds__(256) void conv_frag(const float* __restrict__ src,
                                                 unsigned short* __restrict__ dst,
                                                 int ngroups) {
    int t = blockIdx.x * 256 + threadIdx.x;   // one thread per 8 outputs
    if (t >= ngroups * 256) return;
    int g = t >> 8, rem = t & 255;
    int c = rem >> 6, lane = rem & 63;
    int row = g * 16 + (lane & 15);
    int col = c * 32 + ((lane >> 4) << 3);
    const float* s = src + (size_t)row * 128 + col;
    float4 a0 = *(const float4*)s;
    float4 a1 = *(const float4*)(s + 4);
    uint4 pk = { pack2(a0.x, a0.y), pack2(a0.z, a0.w),
                 pack2(a1.x, a1.y), pack2(a1.z, a1.w) };
    *(uint4*)(dst + (size_t)t * 8) = pk;
}

#define PBLK   2048   // p extent per block
#define PFLUSH 256    // p per flush round

// Main v7: block = 16 q-rows x 2048 p. 4 waves; per 256p flush each wave computes
// 4 x 16p fragments (B frags = coalesced 1KB register loads, no LDS on input path),
// deposits scaled cos into a 16x260 LDS row buffer, then stores COMPLETE 1KB row
// segments. xor is computed inline in the flush phase (no MFMA dependency, no LDS).
// 16.6KB LDS -> 4 blocks/CU = 16 waves/CU; 2048 blocks = 2 staggered generations.
__global__ __launch_bounds__(256, 4) void fused_gemm(
        const unsigned short* __restrict__ Qf, const unsigned short* __restrict__ Pf,
        const int* __restrict__ qid, const int* __restrict__ pid,
        const float* __restrict__ rq, const float* __restrict__ rp,
        float* __restrict__ oxor, float* __restrict__ ocos, int Pn) {
    __shared__ __align__(16) float scos[16 * 260];   // padded stride 260

    // Bijective XCD chunking: XCD x owns a contiguous run of row-panels ->
    // each XCD writes one contiguous ~64MB output slab; Qf slice stays L2-hot.
    const int nwg = gridDim.x;
    const int chunk = nwg >> 3;
    const int bid = blockIdx.x;
    const int wg = (bid & 7) * chunk + (bid >> 3);
    const int nPc = Pn / PBLK;
    const int qg = wg / nPc;           // 16-row group
    const int pc = wg % nPc;
    const int pblock = pc * PBLK;

    const int t = threadIdx.x;
    const int lane = t & 63;
    const int w = t >> 6;
    const int lq = lane & 15;
    const int g4 = (lane >> 4) << 2;   // 0,4,8,12

    // A fragments (shared by all waves): coalesced 1KB loads
    bf16x8 af[4];
    const unsigned short* abase = Qf + ((size_t)(qg * 4) * 64 + lane) * 8;
#pragma unroll
    for (int kk = 0; kk < 4; ++kk)
        af[kk] = *(const bf16x8*)(abase + kk * 512);

    const int qrow_base = qg * 16;
    const float rqv = rq[qrow_base + lq];

    for (int fl = 0; fl < PBLK / PFLUSH; ++fl) {
        const int fbase = pblock + fl * PFLUSH;
        // ---- compute phase: 4 fragments/wave; unrolled so the 16 independent
        // B loads hoist ahead of the MFMAs ----
#pragma unroll
        for (int f = 0; f < 4; ++f) {
            const int cidx = f * 4 + w;          // 16p chunk within flush
            const int p0 = fbase + cidx * 16;
            const unsigned short* bbase = Pf + ((size_t)(p0 >> 4) * 4) * 512 + (size_t)lane * 8;
            bf16x8 bfr[4];
#pragma unroll
            for (int kk = 0; kk < 4; ++kk)
                bfr[kk] = *(const bf16x8*)(bbase + kk * 512);
            f32x4 acc = {0.f, 0.f, 0.f, 0.f};
#pragma unroll
            for (int kk = 0; kk < 4; ++kk)
                acc = __builtin_amdgcn_mfma_f32_16x16x32_bf16(bfr[kk], af[kk], acc, 0, 0, 0);
            // C layout: lane holds q = lane&15, p = (lane>>4)*4 + reg
            const float4 rpv = *(const float4*)(rp + p0 + g4);
            f32x4 c4 = { acc[0]*rqv*rpv.x, acc[1]*rqv*rpv.y,
                         acc[2]*rqv*rpv.z, acc[3]*rqv*rpv.w };
            *(f32x4*)&scos[lq * 260 + cidx * 16 + g4] = c4;
        }
        __syncthreads();
        // ---- flush phase: wave w stores rows 4w..4w+3, 1KB contiguous per
        // store-instr; xor computed inline from pid/qid (L2-hot) ----
        const int4 pv4 = *(const int4*)(pid + fbase + lane * 4);
#pragma unroll
        for (int r = 0; r < 4; ++r) {
            const int row = w * 4 + r;
            const int qvr = qid[qrow_base + row];          // wave-uniform scalar
            const size_t obase = (size_t)(qrow_base + row) * Pn + fbase;
            f32x4 vc = *(const f32x4*)&scos[row * 260 + lane * 4];
            f32x4 vx = { qvr==pv4.x?1.f:0.f, qvr==pv4.y?1.f:0.f,
                         qvr==pv4.z?1.f:0.f, qvr==pv4.w?1.f:0.f };
            __builtin_nontemporal_store(vc, (f32x4*)(ocos + obase + lane * 4));
            __builtin_nontemporal_store(vx, (f32x4*)(oxor + obase + lane * 4));
        }
        __syncthreads();
    }
}

extern "C" void kernel_launch(void* const* d_in, const int* in_sizes, int n_in,
                              void* d_out, int out_size, void* d_ws, size_t ws_size,
                              hipStream_t stream) {
    const int*   qid = (const int*)d_in[0];
    const int*   pid = (const int*)d_in[1];
    const float* qe  = (const float*)d_in[2];
    const float* pe  = (const float*)d_in[3];
    const int Q  = in_sizes[0];   // 4096
    const int Pn = in_sizes[1];   // 16384

    // ws layout: Qf bf16 (Q*128), Pf bf16 (P*128), rq (Q), rp (P)  ~= 5.3 MB
    unsigned short* Qf = (unsigned short*)d_ws;
    unsigned short* Pf = Qf + (size_t)Q * 128;
    float* rq = (float*)(Pf + (size_t)Pn * 128);
    float* rp = rq + Q;

    float* oxor = (float*)d_out;
    float* ocos = oxor + (size_t)Q * (size_t)Pn;

    const int qgroups = Q / 16, pgroups = Pn / 16;
    conv_frag<<<qgroups, 256, 0, stream>>>(qe, Qf, qgroups);
    conv_frag<<<pgroups, 256, 0, stream>>>(pe, Pf, pgroups);
    prep_norms<<<(Q + Pn + 3) / 4, 256, 0, stream>>>(qe, pe, rq, rp, Q, Pn);

    const int nblocks = (Q / 16) * (Pn / PBLK);   // 256 * 8 = 2048
    fused_gemm<<<nblocks, 256, 0, stream>>>(Qf, Pf, qid, pid, rq, rp, oxor, ocos, Pn);
}

// Round 8
// 132.258 us; speedup vs baseline: 2.5210x; 1.0493x over previous
//
#include <hip/hip_runtime.h>
#include <stdint.h>

typedef __attribute__((ext_vector_type(8))) short bf16x8;
typedef __attribute__((ext_vector_type(4))) float f32x4;

__device__ __forceinline__ uint32_t f2bf(float f) {
    uint32_t u = __builtin_bit_cast(uint32_t, f);
    u += 0x7fffu + ((u >> 16) & 1u);   // RNE round to bf16
    return u >> 16;
}
__device__ __forceinline__ uint32_t pack2(float a, float b) {
    return f2bf(a) | (f2bf(b) << 16);
}

// Prep 1: reciprocal norms 1/max(||row||, eps).
__global__ __launch_bounds__(256) void prep_norms(const float* __restrict__ qe,
                                                  const float* __restrict__ pe,
                                                  float* __restrict__ rq,
                                                  float* __restrict__ rp,
                                                  int Q, int Pn) {
    int gw = (blockIdx.x * 256 + threadIdx.x) >> 6;  // one wave per row
    int lane = threadIdx.x & 63;
    if (gw >= Q + Pn) return;
    const float* src = (gw < Q) ? (qe + (size_t)gw * 128) : (pe + (size_t)(gw - Q) * 128);
    float2 v = *(const float2*)(src + lane * 2);
    float s = v.x * v.x + v.y * v.y;
#pragma unroll
    for (int off = 32; off > 0; off >>= 1) s += __shfl_down(s, off, 64);
    if (lane == 0) {
        float r = 1.0f / fmaxf(sqrtf(s), 1e-8f);
        if (gw < Q) rq[gw] = r; else rp[gw - Q] = r;
    }
}

// Prep 2: fp32 [rows][128] -> bf16 in MFMA-fragment order.
// Fragment (g = 16-row group, c = 32-wide k chunk): lane holds row g*16+(lane&15),
// k = c*32+(lane>>4)*8 .. +7. Flat halfword offset = ((g*4+c)*64 + lane)*8.
// A wave's fragment load in the GEMM = 64 contiguous 16B chunks = 1KB coalesced.
__global__ __launch_bounds__(256) void conv_frag(const float* __restrict__ src,
                                                 unsigned short* __restrict__ dst,
                                                 int ngroups) {
    int t = blockIdx.x * 256 + threadIdx.x;   // one thread per 8 outputs
    if (t >= ngroups * 256) return;
    int g = t >> 8, rem = t & 255;
    int c = rem >> 6, lane = rem & 63;
    int row = g * 16 + (lane & 15);
    int col = c * 32 + ((lane >> 4) << 3);
    const float* s = src + (size_t)row * 128 + col;
    float4 a0 = *(const float4*)s;
    float4 a1 = *(const float4*)(s + 4);
    uint4 pk = { pack2(a0.x, a0.y), pack2(a0.z, a0.w),
                 pack2(a1.x, a1.y), pack2(a1.z, a1.w) };
    *(uint4*)(dst + (size_t)t * 8) = pk;
}

#define PBLK 2048   // p extent per block

// Main v8: ZERO barriers. Block = 16 q-rows x 2048p, 4 waves. Each wave owns a
// contiguous 64p span per round; the 16q x 64p transpose is WAVE-PRIVATE through
// a 4KB LDS slice (stride 65 words: ~2-way banks on write, 2-way on read = free).
// Every wave is an independent load->MFMA->LDS->store stream; latency hidden by
// 16 waves/CU of TLP. xor computed inline (no MFMA dependency).
__global__ __launch_bounds__(256, 4) void fused_gemm(
        const unsigned short* __restrict__ Qf, const unsigned short* __restrict__ Pf,
        const int* __restrict__ qid, const int* __restrict__ pid,
        const float* __restrict__ rq, const float* __restrict__ rp,
        float* __restrict__ oxor, float* __restrict__ ocos, int Pn) {
    __shared__ __align__(16) float scos[4 * 16 * 65];   // 16.6KB, per-wave slices

    // Bijective XCD chunking: XCD x owns a contiguous run of row-panels ->
    // contiguous ~64MB output slab per XCD; Qf slice stays L2-hot.
    const int nwg = gridDim.x;
    const int chunk = nwg >> 3;
    const int bid = blockIdx.x;
    const int wg = (bid & 7) * chunk + (bid >> 3);
    const int nPc = Pn / PBLK;
    const int qg = wg / nPc;           // 16-row q group
    const int pc = wg % nPc;
    const int pblock = pc * PBLK;

    const int t = threadIdx.x;
    const int lane = t & 63;
    const int w = t >> 6;
    const int lq = lane & 15;
    const int g4 = (lane >> 4) << 2;   // 0,4,8,12
    const int wbase = w * (16 * 65);   // this wave's private LDS slice (words)

    // A fragments (shared rows for all waves): coalesced 1KB loads
    bf16x8 af[4];
    const unsigned short* abase = Qf + ((size_t)(qg * 4) * 64 + lane) * 8;
#pragma unroll
    for (int kk = 0; kk < 4; ++kk)
        af[kk] = *(const bf16x8*)(abase + kk * 512);

    const int qrow_base = qg * 16;
    const float rqv = rq[qrow_base + lq];

    for (int fl = 0; fl < PBLK / 256; ++fl) {
        const int pw = pblock + fl * 256 + w * 64;   // this wave's 64p span
        // ---- compute: 4 fragments = 64p, deposit scaled cos into private slice ----
#pragma unroll
        for (int f = 0; f < 4; ++f) {
            const int p0 = pw + f * 16;
            const unsigned short* bbase = Pf + (size_t)(p0 >> 4) * 2048 + (size_t)lane * 8;
            bf16x8 bfr[4];
#pragma unroll
            for (int kk = 0; kk < 4; ++kk)
                bfr[kk] = *(const bf16x8*)(bbase + kk * 512);
            f32x4 acc = {0.f, 0.f, 0.f, 0.f};
#pragma unroll
            for (int kk = 0; kk < 4; ++kk)
                acc = __builtin_amdgcn_mfma_f32_16x16x32_bf16(bfr[kk], af[kk], acc, 0, 0, 0);
            // C layout: lane holds q = lane&15, p = p0 + (lane>>4)*4 + reg
            const float4 rpv = *(const float4*)(rp + p0 + g4);
            const int a0 = wbase + lq * 65 + f * 16 + g4;
            scos[a0 + 0] = acc[0] * rqv * rpv.x;
            scos[a0 + 1] = acc[1] * rqv * rpv.y;
            scos[a0 + 2] = acc[2] * rqv * rpv.z;
            scos[a0 + 3] = acc[3] * rqv * rpv.w;
        }
        // ---- flush (same wave, no barrier): 16 rows x 256B contiguous ----
        const int pvl = pid[pw + lane];
#pragma unroll
        for (int r = 0; r < 16; ++r) {
            const int qvr = qid[qrow_base + r];            // wave-uniform
            const size_t obase = (size_t)(qrow_base + r) * Pn + pw;
            float vc = scos[wbase + r * 65 + lane];
            float vx = (qvr == pvl) ? 1.f : 0.f;
            __builtin_nontemporal_store(vc, ocos + obase + lane);
            __builtin_nontemporal_store(vx, oxor + obase + lane);
        }
    }
}

extern "C" void kernel_launch(void* const* d_in, const int* in_sizes, int n_in,
                              void* d_out, int out_size, void* d_ws, size_t ws_size,
                              hipStream_t stream) {
    const int*   qid = (const int*)d_in[0];
    const int*   pid = (const int*)d_in[1];
    const float* qe  = (const float*)d_in[2];
    const float* pe  = (const float*)d_in[3];
    const int Q  = in_sizes[0];   // 4096
    const int Pn = in_sizes[1];   // 16384

    // ws layout: Qf bf16 (Q*128), Pf bf16 (P*128), rq (Q), rp (P)  ~= 5.3 MB
    unsigned short* Qf = (unsigned short*)d_ws;
    unsigned short* Pf = Qf + (size_t)Q * 128;
    float* rq = (float*)(Pf + (size_t)Pn * 128);
    float* rp = rq + Q;

    float* oxor = (float*)d_out;
    float* ocos = oxor + (size_t)Q * (size_t)Pn;

    const int qgroups = Q / 16, pgroups = Pn / 16;
    conv_frag<<<qgroups, 256, 0, stream>>>(qe, Qf, qgroups);
    conv_frag<<<pgroups, 256, 0, stream>>>(pe, Pf, pgroups);
    prep_norms<<<(Q + Pn + 3) / 4, 256, 0, stream>>>(qe, pe, rq, rp, Q, Pn);

    const int nblocks = (Q / 16) * (Pn / PBLK);   // 256 * 8 = 2048
    fused_gemm<<<nblocks, 256, 0, stream>>>(Qf, Pf, qid, pid, rq, rp, oxor, ocos, Pn);
}